// Round 1
// baseline (451.465 us; speedup 1.0000x reference)
//
#include <hip/hip_runtime.h>
#include <math.h>

#define ALPHA_F 0.4f
#define FP32_EPS 1.1920928955078125e-7f
#define NB 256
#define NV 128000
#define NR 64

typedef _Float16 half_t;
typedef _Float16 half2_t __attribute__((ext_vector_type(2)));
typedef _Float16 half4_t __attribute__((ext_vector_type(4)));
typedef _Float16 half8 __attribute__((ext_vector_type(8)));
typedef float f32x4 __attribute__((ext_vector_type(4)));

// ---------------------------------------------------------------------------
// Scratch layouts.
// FAST (ws_size >= 140 MB; observed ~524 MB poison fill => expect FAST):
//   ws +0      : maxbits[2]
//   ws +256    : P[256*64] f32
//   ws +1  MiB : Ppart  (250 x 4 x 64x64 f32, 16.4 MB)
//   ws +34 MiB : Wg     (k1 B-frags fp16, 16.4 MB)
//   ws +51 MiB : Wf     (k2/k3 B-frags fp16, 16.4 MB)
//   ws +68 MiB : Lh     (L as fp16, 65.5 MB)
// FALLBACK: maxbits/P in ws; Ppart @ d_out+0 (16.4 MB), Wg @ d_out+33MiB (dead
//   before k3); no Wf/Lh — k2/k3 read fp32 L and W directly.
// ---------------------------------------------------------------------------

// ---------- k0: build fp16 W fragments; zero P / maxbits ----------
__global__ __launch_bounds__(256) void k0_prep(const float* __restrict__ W,
                                               half_t* __restrict__ Wg,
                                               half_t* __restrict__ Wf,
                                               float* __restrict__ P,
                                               unsigned* __restrict__ maxbits) {
    __shared__ half_t tile[256 * 72];   // stride 72 halves = 144 B (16B-aligned rows)
    const int t  = threadIdx.x;
    const int k0 = blockIdx.x * 256;

    if (blockIdx.x < 64) P[blockIdx.x * 256 + t] = 0.f;
    if (blockIdx.x == 0 && t < 2) maxbits[t] = 0u;

    // coalesced read of W[256k x 64n] tile, cvt fp16 -> LDS
#pragma unroll
    for (int i = 0; i < 16; ++i) {
        const int f  = i * 256 + t;
        const int kr = f >> 4;
        const int n4 = (f & 15) * 4;
        const float4 v = *(const float4*)(W + (size_t)(k0 + kr) * NR + n4);
        half2_t h01 = { (half_t)v.x, (half_t)v.y };
        half2_t h23 = { (half_t)v.z, (half_t)v.w };
        *(half2_t*)&tile[kr * 72 + n4]     = h01;
        *(half2_t*)&tile[kr * 72 + n4 + 2] = h23;
    }
    __syncthreads();

    // Wg: B-frags for P = L@W (transposed gather). frag(kt,nt,lane=(q,il))[j]
    //   = W[kt*32 + q*8 + j][nt*16 + il]
#pragma unroll
    for (int i = 0; i < 8; ++i) {
        const int idx  = i * 256 + t;        // 0..2047
        const int kk_l = idx >> 8;           // 0..7
        const int rem  = idx & 255;
        const int nt   = rem >> 6;
        const int lane = rem & 63;
        const int q = lane >> 4, il = lane & 15;
        half8 v;
#pragma unroll
        for (int j = 0; j < 8; ++j)
            v[j] = tile[(kk_l * 32 + q * 8 + j) * 72 + nt * 16 + il];
        const int kt = blockIdx.x * 8 + kk_l;
        *(half8*)(Wg + ((size_t)(kt * 4 + nt) * 64 + lane) * 8) = v;
    }

    // Wf: B-frags for Lp = P@W^T (no transpose). frag(vt,ks,lane=(q,il))[j]
    //   = W[vt*16 + il][ks*32 + q*8 + j]   (contiguous ds_read_b128)
    if (Wf) {
#pragma unroll
        for (int i = 0; i < 8; ++i) {
            const int idx  = i * 256 + t;
            const int vt_l = idx >> 7;       // 0..15
            const int ks   = (idx >> 6) & 1;
            const int lane = idx & 63;
            const int q = lane >> 4, il = lane & 15;
            half8 v = *(const half8*)&tile[(vt_l * 16 + il) * 72 + ks * 32 + q * 8];
            const int vt = blockIdx.x * 16 + vt_l;
            *(half8*)(Wf + ((size_t)(vt * 2 + ks) * 64 + lane) * 8) = v;
        }
    }
}

// ---------- k1: split-K MFMA partials of P = L @ W; emit Lh; max|L| ----------
// grid (250 K-superchunks of 1024, 4 m-quarters); block 256 = 4 waves.
// Each block owns 2 chunks of 256 K = 16 K-steps, register-accumulated, with an
// explicit 2-deep load double-buffer (ba/fa <-> bb/fb) so the next K-step's 6
// global loads are in flight during the current cvt/MFMA body.
#define K1_NIT 16

#define K1_LOADB(dst, it) do {                                                   \
    const half_t* wp_ = Wg + ((size_t)((kt0 + (it)) * 4) * 64 + l) * 8;          \
    dst[0] = *(const half8*)(wp_);                                               \
    dst[1] = *(const half8*)(wp_ + 64 * 8);                                      \
    dst[2] = *(const half8*)(wp_ + 2 * 64 * 8);                                  \
    dst[3] = *(const half8*)(wp_ + 3 * 64 * 8); } while (0)

#define K1_LOADL(d0, d1, it) do {                                                \
    const float* lp_ = L + rowbase + (kt0 + (it)) * 32 + q * 8;                  \
    d0 = *(const float4*)lp_;                                                    \
    d1 = *(const float4*)(lp_ + 4); } while (0)

#define K1_BODY(f0v, f1v, bv, it) do {                                           \
    amax = fmaxf(amax, fmaxf(fmaxf(fabsf(f0v.x), fabsf(f0v.y)),                  \
                             fmaxf(fabsf(f0v.z), fabsf(f0v.w))));                \
    amax = fmaxf(amax, fmaxf(fmaxf(fabsf(f1v.x), fabsf(f1v.y)),                  \
                             fmaxf(fabsf(f1v.z), fabsf(f1v.w))));                \
    half8 a_ = { (half_t)f0v.x, (half_t)f0v.y, (half_t)f0v.z, (half_t)f0v.w,     \
                 (half_t)f1v.x, (half_t)f1v.y, (half_t)f1v.z, (half_t)f1v.w };   \
    if (Lh) *(half8*)(Lh + rowbase + (kt0 + (it)) * 32 + q * 8) = a_;            \
    acc[0] = __builtin_amdgcn_mfma_f32_16x16x32_f16(a_, bv[0], acc[0], 0, 0, 0); \
    acc[1] = __builtin_amdgcn_mfma_f32_16x16x32_f16(a_, bv[1], acc[1], 0, 0, 0); \
    acc[2] = __builtin_amdgcn_mfma_f32_16x16x32_f16(a_, bv[2], acc[2], 0, 0, 0); \
    acc[3] = __builtin_amdgcn_mfma_f32_16x16x32_f16(a_, bv[3], acc[3], 0, 0, 0); } while (0)

__global__ __launch_bounds__(256, 4) void k1_pmm(const float* __restrict__ L,
                                                 const half_t* __restrict__ Wg,
                                                 float* __restrict__ Ppart,
                                                 half_t* __restrict__ Lh,
                                                 unsigned* __restrict__ maxbits) {
    const int l  = threadIdx.x & 63;
    const int w  = threadIdx.x >> 6;
    const int q  = l >> 4;
    const int il = l & 15;
    const int mq    = blockIdx.y;
    const int row   = mq * 64 + w * 16 + il;
    const size_t rowbase = (size_t)row * NV;
    const int kt0 = blockIdx.x * K1_NIT;   // K-step index (each step = 32 K)

    f32x4 acc[4] = {};
    float amax = 0.f;

    float4 fa0, fa1, fb0, fb1;
    half8 ba[4], bb[4];

    // prologue: it = 0 into buffer A
    K1_LOADB(ba, 0);
    K1_LOADL(fa0, fa1, 0);

#pragma unroll
    for (int it = 0; it < K1_NIT; it += 2) {
        // prefetch it+1 into B while computing it from A
        K1_LOADB(bb, it + 1);
        K1_LOADL(fb0, fb1, it + 1);
        K1_BODY(fa0, fa1, ba, it);
        // prefetch it+2 into A while computing it+1 from B
        if (it + 2 < K1_NIT) {
            K1_LOADB(ba, it + 2);
            K1_LOADL(fa0, fa1, it + 2);
        }
        K1_BODY(fb0, fb1, bb, it + 1);
    }

    float* pb = Ppart + (size_t)(blockIdx.x * 4 + mq) * 4096;
#pragma unroll
    for (int nt = 0; nt < 4; ++nt)
#pragma unroll
        for (int i = 0; i < 4; ++i)
            pb[(w * 16 + q * 4 + i) * 64 + nt * 16 + il] = acc[nt][i];

#pragma unroll
    for (int off = 32; off > 0; off >>= 1)
        amax = fmaxf(amax, __shfl_xor(amax, off, 64));
    __shared__ float red[4];
    if (l == 0) red[w] = amax;
    __syncthreads();
    if (threadIdx.x == 0) {
        float m = fmaxf(fmaxf(red[0], red[1]), fmaxf(red[2], red[3]));
        atomicMax(&maxbits[0], __float_as_uint(m));
    }
}

// ---------- k1b: reduce Ppart -> P (atomicAdd partial sums) ----------
// 250 partials; grid (64, 10): y handles chunks [y*25, y*25+25)
__global__ __launch_bounds__(256) void k1b_reduce(const float* __restrict__ Ppart,
                                                  float* __restrict__ P) {
    const int g  = blockIdx.x * 256 + threadIdx.x;  // 0..16383
    const int M  = g >> 6, n = g & 63;
    const int mq = M >> 6, r = M & 63;
    const float* p = Ppart + ((size_t)(blockIdx.y * 25) * 4 + mq) * 4096 + r * 64 + n;
    float s = 0.f;
#pragma unroll 5
    for (int c = 0; c < 25; ++c) s += p[(size_t)c * 4 * 4096];
    atomicAdd(&P[g], s);
}

// ---------- k2/k3: T = P@W^T tile -> LDS; streaming epilogue ----------
// grid (1000 n-chunks of 128, 4 m-quarters); block 256; LDS T[64][132].
template <bool FAST, bool IS_OUT>
__global__ __launch_bounds__(256) void k23(const float* __restrict__ L,
                                           const half_t* __restrict__ Lh,
                                           const float* __restrict__ W,
                                           const half_t* __restrict__ Wf,
                                           const float* __restrict__ P,
                                           unsigned* __restrict__ maxbits,
                                           float* __restrict__ out) {
    __shared__ float T[64 * 132];
    __shared__ float red[4];
    const int l  = threadIdx.x & 63;
    const int w  = threadIdx.x >> 6;
    const int q  = l >> 4;
    const int il = l & 15;
    const int nc = blockIdx.x;
    const int mq = blockIdx.y;

    // phase A: MFMA 64 rows x 128 cols; wave w covers cols w*32..+32
    half8 a[4][2];
#pragma unroll
    for (int mt = 0; mt < 4; ++mt)
#pragma unroll
        for (int ks = 0; ks < 2; ++ks) {
            const float* pp = P + (size_t)(mq * 64 + mt * 16 + il) * NR + ks * 32 + q * 8;
            const float4 f0 = *(const float4*)pp;
            const float4 f1 = *(const float4*)(pp + 4);
            a[mt][ks] = { (half_t)f0.x, (half_t)f0.y, (half_t)f0.z, (half_t)f0.w,
                          (half_t)f1.x, (half_t)f1.y, (half_t)f1.z, (half_t)f1.w };
        }
#pragma unroll
    for (int ntl = 0; ntl < 2; ++ntl) {
        const int vt = nc * 8 + w * 2 + ntl;
        half8 b[2];
        if (FAST) {
#pragma unroll
            for (int ks = 0; ks < 2; ++ks)
                b[ks] = *(const half8*)(Wf + ((size_t)(vt * 2 + ks) * 64 + l) * 8);
        } else {
#pragma unroll
            for (int ks = 0; ks < 2; ++ks) {
                const float* wp = W + (size_t)(vt * 16 + il) * NR + ks * 32 + q * 8;
                const float4 f0 = *(const float4*)wp;
                const float4 f1 = *(const float4*)(wp + 4);
                b[ks] = { (half_t)f0.x, (half_t)f0.y, (half_t)f0.z, (half_t)f0.w,
                          (half_t)f1.x, (half_t)f1.y, (half_t)f1.z, (half_t)f1.w };
            }
        }
#pragma unroll
        for (int mt = 0; mt < 4; ++mt) {
            f32x4 acc = {};
            acc = __builtin_amdgcn_mfma_f32_16x16x32_f16(a[mt][0], b[0], acc, 0, 0, 0);
            acc = __builtin_amdgcn_mfma_f32_16x16x32_f16(a[mt][1], b[1], acc, 0, 0, 0);
#pragma unroll
            for (int i = 0; i < 4; ++i)
                T[(mt * 16 + q * 4 + i) * 132 + w * 32 + ntl * 16 + il] = acc[i];
        }
    }
    __syncthreads();

    // phase B: coalesced streaming over the 64x128 tile
    float c1 = 0.f, mx = 0.f;
    if (IS_OUT) {
        const float maxL  = __uint_as_float(maxbits[0]);
        const float maxLp = fmaxf(__uint_as_float(maxbits[1]), FP32_EPS);
        c1 = (1.f - ALPHA_F) * (maxL / maxLp);
    }
#pragma unroll
    for (int i = 0; i < 8; ++i) {
        const int e = i * 1024 + threadIdx.x * 4;
        const int r = e >> 7, c = e & 127;
        const size_t gaddr = (size_t)(mq * 64 + r) * NV + nc * 128 + c;
        const float4 tv = *(const float4*)&T[r * 132 + c];
        float4 lv;
        if (FAST) {
            const half4_t lh = *(const half4_t*)(Lh + gaddr);
            lv = make_float4((float)lh[0], (float)lh[1], (float)lh[2], (float)lh[3]);
        } else {
            lv = *(const float4*)(L + gaddr);
        }
        if (IS_OUT) {
            float4 o;
            o.x = fmaf(c1, tv.x - lv.x, ALPHA_F * lv.x);
            o.y = fmaf(c1, tv.y - lv.y, ALPHA_F * lv.y);
            o.z = fmaf(c1, tv.z - lv.z, ALPHA_F * lv.z);
            o.w = fmaf(c1, tv.w - lv.w, ALPHA_F * lv.w);
            *(float4*)(out + gaddr) = o;
        } else {
            mx = fmaxf(mx, fmaxf(fmaxf(fabsf(tv.x - lv.x), fabsf(tv.y - lv.y)),
                                 fmaxf(fabsf(tv.z - lv.z), fabsf(tv.w - lv.w))));
        }
    }
    if (!IS_OUT) {
#pragma unroll
        for (int off = 32; off > 0; off >>= 1)
            mx = fmaxf(mx, __shfl_xor(mx, off, 64));
        if (l == 0) red[w] = mx;
        __syncthreads();
        if (threadIdx.x == 0) {
            float m = fmaxf(fmaxf(red[0], red[1]), fmaxf(red[2], red[3]));
            atomicMax(&maxbits[1], __float_as_uint(m));
        }
    }
}

extern "C" void kernel_launch(void* const* d_in, const int* in_sizes, int n_in,
                              void* d_out, int out_size, void* d_ws, size_t ws_size,
                              hipStream_t stream) {
    const float* L = (const float*)d_in[1];   // logits [256,128000] fp32
    const float* W = (const float*)d_in[2];   // W [128000,64] fp32
    float* out = (float*)d_out;

    unsigned* maxbits = (unsigned*)d_ws;
    float*    P       = (float*)((char*)d_ws + 256);

    const bool fast = ws_size >= (size_t)140 * 1024 * 1024;
    float* Ppart; half_t* Wg; half_t* Wf; half_t* Lh;
    char* ws = (char*)d_ws;
    if (fast) {
        Ppart = (float*)(ws + ((size_t)1  << 20));
        Wg    = (half_t*)(ws + ((size_t)34 << 20));
        Wf    = (half_t*)(ws + ((size_t)51 << 20));
        Lh    = (half_t*)(ws + ((size_t)68 << 20));
    } else {
        Ppart = (float*)d_out;                             // dead before k3
        Wg    = (half_t*)((char*)d_out + ((size_t)33 << 20));
        Wf    = nullptr;
        Lh    = nullptr;
    }

    k0_prep   <<<500,           256, 0, stream>>>(W, Wg, Wf, P, maxbits);
    k1_pmm    <<<dim3(250, 4),  256, 0, stream>>>(L, Wg, Ppart, Lh, maxbits);
    k1b_reduce<<<dim3(64, 10),  256, 0, stream>>>(Ppart, P);
    if (fast) {
        k23<true,  false><<<dim3(1000, 4), 256, 0, stream>>>(L, Lh, W, Wf, P, maxbits, out);
        k23<true,  true ><<<dim3(1000, 4), 256, 0, stream>>>(L, Lh, W, Wf, P, maxbits, out);
    } else {
        k23<false, false><<<dim3(1000, 4), 256, 0, stream>>>(L, Lh, W, Wf, P, maxbits, out);
        k23<false, true ><<<dim3(1000, 4), 256, 0, stream>>>(L, Lh, W, Wf, P, maxbits, out);
    }
}

// Round 2
// 370.365 us; speedup vs baseline: 1.2190x; 1.2190x over previous
//
#include <hip/hip_runtime.h>
#include <math.h>

#define ALPHA_F 0.4f
#define FP32_EPS 1.1920928955078125e-7f
#define NB 256
#define NV 128000
#define NR 64

typedef _Float16 half_t;
typedef _Float16 half2_t __attribute__((ext_vector_type(2)));
typedef _Float16 half4_t __attribute__((ext_vector_type(4)));
typedef _Float16 half8 __attribute__((ext_vector_type(8)));
typedef float f32x4 __attribute__((ext_vector_type(4)));

// ---------------------------------------------------------------------------
// Scratch layouts.
// FAST (ws_size >= 140 MB; observed ~524 MB poison fill => expect FAST):
//   ws +0      : maxbits[2]
//   ws +256    : P[256*64] f32
//   ws +1  MiB : Ppart  (500 x 4 x 64x64 f32, 32.8 MB)
//   ws +34 MiB : Wg     (k1 B-frags fp16, 16.4 MB)
//   ws +51 MiB : Wf     (k2/k3 B-frags fp16, 16.4 MB)
//   ws +68 MiB : Lh     (L as fp16, 65.5 MB)
// FALLBACK: maxbits/P in ws; Ppart @ d_out+0, Wg @ d_out+33MiB (dead before
//   k3); no Wf/Lh — k2/k3 read fp32 L and W directly.
// ---------------------------------------------------------------------------

// ---------- k0: build fp16 W fragments; zero P / maxbits ----------
__global__ __launch_bounds__(256) void k0_prep(const float* __restrict__ W,
                                               half_t* __restrict__ Wg,
                                               half_t* __restrict__ Wf,
                                               float* __restrict__ P,
                                               unsigned* __restrict__ maxbits) {
    __shared__ half_t tile[256 * 72];   // stride 72 halves = 144 B (16B-aligned rows)
    const int t  = threadIdx.x;
    const int k0 = blockIdx.x * 256;

    if (blockIdx.x < 64) P[blockIdx.x * 256 + t] = 0.f;
    if (blockIdx.x == 0 && t < 2) maxbits[t] = 0u;

    // coalesced read of W[256k x 64n] tile, cvt fp16 -> LDS
#pragma unroll
    for (int i = 0; i < 16; ++i) {
        const int f  = i * 256 + t;
        const int kr = f >> 4;
        const int n4 = (f & 15) * 4;
        const float4 v = *(const float4*)(W + (size_t)(k0 + kr) * NR + n4);
        half2_t h01 = { (half_t)v.x, (half_t)v.y };
        half2_t h23 = { (half_t)v.z, (half_t)v.w };
        *(half2_t*)&tile[kr * 72 + n4]     = h01;
        *(half2_t*)&tile[kr * 72 + n4 + 2] = h23;
    }
    __syncthreads();

    // Wg: B-frags for P = L@W (transposed gather). frag(kt,nt,lane=(q,il))[j]
    //   = W[kt*32 + q*8 + j][nt*16 + il]
#pragma unroll
    for (int i = 0; i < 8; ++i) {
        const int idx  = i * 256 + t;        // 0..2047
        const int kk_l = idx >> 8;           // 0..7
        const int rem  = idx & 255;
        const int nt   = rem >> 6;
        const int lane = rem & 63;
        const int q = lane >> 4, il = lane & 15;
        half8 v;
#pragma unroll
        for (int j = 0; j < 8; ++j)
            v[j] = tile[(kk_l * 32 + q * 8 + j) * 72 + nt * 16 + il];
        const int kt = blockIdx.x * 8 + kk_l;
        *(half8*)(Wg + ((size_t)(kt * 4 + nt) * 64 + lane) * 8) = v;
    }

    // Wf: B-frags for Lp = P@W^T (no transpose). frag(vt,ks,lane=(q,il))[j]
    //   = W[vt*16 + il][ks*32 + q*8 + j]   (contiguous ds_read_b128)
    if (Wf) {
#pragma unroll
        for (int i = 0; i < 8; ++i) {
            const int idx  = i * 256 + t;
            const int vt_l = idx >> 7;       // 0..15
            const int ks   = (idx >> 6) & 1;
            const int lane = idx & 63;
            const int q = lane >> 4, il = lane & 15;
            half8 v = *(const half8*)&tile[(vt_l * 16 + il) * 72 + ks * 32 + q * 8];
            const int vt = blockIdx.x * 16 + vt_l;
            *(half8*)(Wf + ((size_t)(vt * 2 + ks) * 64 + lane) * 8) = v;
        }
    }
}

// ---------- k1: split-K MFMA partials of P = L @ W; emit Lh; max|L| ----------
// grid (500 K-chunks of 256, 4 m-quarters); block 256 = 4 waves.
// NEW STRUCTURE: every global instruction is contiguous.
//   phase S (stage): coalesced float4 reads of the 64x256 L tile (1 KB/wave
//     instr, full lines, one row each), fp32 amax + fp16 cvt in regs, Lh store
//     straight from regs (8 FULL 128-B lines per wave instr — no partial-line
//     write-allocate), fp16 tile -> LDS with XOR swizzle (G4: 512-B row
//     stride, byte ^= (row&7)<<4).
//   phase M: A-frags via swizzled ds_read_b128 (bank-optimal), Wg frags via
//     contiguous 1-KB global loads, 4 MFMA per K-step.
__global__ __launch_bounds__(256) void k1_pmm(const float* __restrict__ L,
                                              const half_t* __restrict__ Wg,
                                              float* __restrict__ Ppart,
                                              half_t* __restrict__ Lh,
                                              unsigned* __restrict__ maxbits) {
    __shared__ char lds[64 * 512];      // 64 rows x 256 halves (512 B/row), 32 KB
    __shared__ float red[4];
    const int t  = threadIdx.x;
    const int l  = t & 63;
    const int w  = t >> 6;
    const int q  = l >> 4;
    const int il = l & 15;
    const int chunk = blockIdx.x;
    const int mq    = blockIdx.y;
    const int row0  = mq * 64;
    const int col0  = chunk * 256;

    float amax = 0.f;

    // ---- phase S: stage L tile (coalesced), emit Lh, fill swizzled LDS ----
    {
        const int tr = t >> 5;          // 0..7  (row within pass-stripe)
        const int tc = t & 31;          // 0..31 (8-col chunk)
#pragma unroll
        for (int p = 0; p < 8; ++p) {
            const int r = p * 8 + tr;   // 0..63 ; r&7 == tr
            const size_t g = (size_t)(row0 + r) * NV + col0 + tc * 8;
            const float4 f0 = *(const float4*)(L + g);
            const float4 f1 = *(const float4*)(L + g + 4);
            amax = fmaxf(amax, fmaxf(fmaxf(fabsf(f0.x), fabsf(f0.y)),
                                     fmaxf(fabsf(f0.z), fabsf(f0.w))));
            amax = fmaxf(amax, fmaxf(fmaxf(fabsf(f1.x), fabsf(f1.y)),
                                     fmaxf(fabsf(f1.z), fabsf(f1.w))));
            half8 h = { (half_t)f0.x, (half_t)f0.y, (half_t)f0.z, (half_t)f0.w,
                        (half_t)f1.x, (half_t)f1.y, (half_t)f1.z, (half_t)f1.w };
            if (Lh) *(half8*)(Lh + g) = h;
            const int off = r * 512 + ((tc * 16) ^ (tr << 4));
            *(half8*)(lds + off) = h;
        }
    }
    __syncthreads();

    // ---- phase M: MFMA over 8 K-steps ----
    f32x4 acc[4] = {};
    const int arow = w * 16 + il;
    const int abase = arow * 512;
    const int axor  = (il & 7) << 4;
#pragma unroll
    for (int ks = 0; ks < 8; ++ks) {
        const int kt = chunk * 8 + ks;
        half8 b[4];
#pragma unroll
        for (int nt = 0; nt < 4; ++nt)
            b[nt] = *(const half8*)(Wg + ((size_t)(kt * 4 + nt) * 64 + l) * 8);
        const half8 a = *(const half8*)(lds + ((abase + ks * 64 + q * 16) ^ axor));
#pragma unroll
        for (int nt = 0; nt < 4; ++nt)
            acc[nt] = __builtin_amdgcn_mfma_f32_16x16x32_f16(a, b[nt], acc[nt], 0, 0, 0);
    }

    float* pb = Ppart + (size_t)(chunk * 4 + mq) * 4096;
#pragma unroll
    for (int nt = 0; nt < 4; ++nt)
#pragma unroll
        for (int i = 0; i < 4; ++i)
            pb[(w * 16 + q * 4 + i) * 64 + nt * 16 + il] = acc[nt][i];

#pragma unroll
    for (int off = 32; off > 0; off >>= 1)
        amax = fmaxf(amax, __shfl_xor(amax, off, 64));
    if (l == 0) red[w] = amax;
    __syncthreads();
    if (threadIdx.x == 0) {
        float m = fmaxf(fmaxf(red[0], red[1]), fmaxf(red[2], red[3]));
        atomicMax(&maxbits[0], __float_as_uint(m));
    }
}

// ---------- k1b: reduce Ppart -> P (atomicAdd partial sums) ----------
// grid (64, 5): y handles chunks [y*100, y*100+100)
__global__ __launch_bounds__(256) void k1b_reduce(const float* __restrict__ Ppart,
                                                  float* __restrict__ P) {
    const int g  = blockIdx.x * 256 + threadIdx.x;  // 0..16383
    const int M  = g >> 6, n = g & 63;
    const int mq = M >> 6, r = M & 63;
    const float* p = Ppart + ((size_t)(blockIdx.y * 100) * 4 + mq) * 4096 + r * 64 + n;
    float s = 0.f;
#pragma unroll 4
    for (int c = 0; c < 100; ++c) s += p[(size_t)c * 4 * 4096];
    atomicAdd(&P[g], s);
}

// ---------- k2/k3: T = P@W^T tile -> LDS; streaming epilogue ----------
// grid (1000 n-chunks of 128, 4 m-quarters); block 256; LDS T[64][132].
template <bool FAST, bool IS_OUT>
__global__ __launch_bounds__(256) void k23(const float* __restrict__ L,
                                           const half_t* __restrict__ Lh,
                                           const float* __restrict__ W,
                                           const half_t* __restrict__ Wf,
                                           const float* __restrict__ P,
                                           unsigned* __restrict__ maxbits,
                                           float* __restrict__ out) {
    __shared__ float T[64 * 132];
    __shared__ float red[4];
    const int l  = threadIdx.x & 63;
    const int w  = threadIdx.x >> 6;
    const int q  = l >> 4;
    const int il = l & 15;
    const int nc = blockIdx.x;
    const int mq = blockIdx.y;

    // phase A: MFMA 64 rows x 128 cols; wave w covers cols w*32..+32
    half8 a[4][2];
#pragma unroll
    for (int mt = 0; mt < 4; ++mt)
#pragma unroll
        for (int ks = 0; ks < 2; ++ks) {
            const float* pp = P + (size_t)(mq * 64 + mt * 16 + il) * NR + ks * 32 + q * 8;
            const float4 f0 = *(const float4*)pp;
            const float4 f1 = *(const float4*)(pp + 4);
            a[mt][ks] = { (half_t)f0.x, (half_t)f0.y, (half_t)f0.z, (half_t)f0.w,
                          (half_t)f1.x, (half_t)f1.y, (half_t)f1.z, (half_t)f1.w };
        }
#pragma unroll
    for (int ntl = 0; ntl < 2; ++ntl) {
        const int vt = nc * 8 + w * 2 + ntl;
        half8 b[2];
        if (FAST) {
#pragma unroll
            for (int ks = 0; ks < 2; ++ks)
                b[ks] = *(const half8*)(Wf + ((size_t)(vt * 2 + ks) * 64 + l) * 8);
        } else {
#pragma unroll
            for (int ks = 0; ks < 2; ++ks) {
                const float* wp = W + (size_t)(vt * 16 + il) * NR + ks * 32 + q * 8;
                const float4 f0 = *(const float4*)wp;
                const float4 f1 = *(const float4*)(wp + 4);
                b[ks] = { (half_t)f0.x, (half_t)f0.y, (half_t)f0.z, (half_t)f0.w,
                          (half_t)f1.x, (half_t)f1.y, (half_t)f1.z, (half_t)f1.w };
            }
        }
#pragma unroll
        for (int mt = 0; mt < 4; ++mt) {
            f32x4 acc = {};
            acc = __builtin_amdgcn_mfma_f32_16x16x32_f16(a[mt][0], b[0], acc, 0, 0, 0);
            acc = __builtin_amdgcn_mfma_f32_16x16x32_f16(a[mt][1], b[1], acc, 0, 0, 0);
#pragma unroll
            for (int i = 0; i < 4; ++i)
                T[(mt * 16 + q * 4 + i) * 132 + w * 32 + ntl * 16 + il] = acc[i];
        }
    }
    __syncthreads();

    // phase B: coalesced streaming over the 64x128 tile
    float c1 = 0.f, mx = 0.f;
    if (IS_OUT) {
        const float maxL  = __uint_as_float(maxbits[0]);
        const float maxLp = fmaxf(__uint_as_float(maxbits[1]), FP32_EPS);
        c1 = (1.f - ALPHA_F) * (maxL / maxLp);
    }
#pragma unroll
    for (int i = 0; i < 8; ++i) {
        const int e = i * 1024 + threadIdx.x * 4;
        const int r = e >> 7, c = e & 127;
        const size_t gaddr = (size_t)(mq * 64 + r) * NV + nc * 128 + c;
        const float4 tv = *(const float4*)&T[r * 132 + c];
        float4 lv;
        if (FAST) {
            const half4_t lh = *(const half4_t*)(Lh + gaddr);
            lv = make_float4((float)lh[0], (float)lh[1], (float)lh[2], (float)lh[3]);
        } else {
            lv = *(const float4*)(L + gaddr);
        }
        if (IS_OUT) {
            float4 o;
            o.x = fmaf(c1, tv.x - lv.x, ALPHA_F * lv.x);
            o.y = fmaf(c1, tv.y - lv.y, ALPHA_F * lv.y);
            o.z = fmaf(c1, tv.z - lv.z, ALPHA_F * lv.z);
            o.w = fmaf(c1, tv.w - lv.w, ALPHA_F * lv.w);
            *(float4*)(out + gaddr) = o;
        } else {
            mx = fmaxf(mx, fmaxf(fmaxf(fabsf(tv.x - lv.x), fabsf(tv.y - lv.y)),
                                 fmaxf(fabsf(tv.z - lv.z), fabsf(tv.w - lv.w))));
        }
    }
    if (!IS_OUT) {
#pragma unroll
        for (int off = 32; off > 0; off >>= 1)
            mx = fmaxf(mx, __shfl_xor(mx, off, 64));
        if (l == 0) red[w] = mx;
        __syncthreads();
        if (threadIdx.x == 0) {
            float m = fmaxf(fmaxf(red[0], red[1]), fmaxf(red[2], red[3]));
            atomicMax(&maxbits[1], __float_as_uint(m));
        }
    }
}

extern "C" void kernel_launch(void* const* d_in, const int* in_sizes, int n_in,
                              void* d_out, int out_size, void* d_ws, size_t ws_size,
                              hipStream_t stream) {
    const float* L = (const float*)d_in[1];   // logits [256,128000] fp32
    const float* W = (const float*)d_in[2];   // W [128000,64] fp32
    float* out = (float*)d_out;

    unsigned* maxbits = (unsigned*)d_ws;
    float*    P       = (float*)((char*)d_ws + 256);

    const bool fast = ws_size >= (size_t)140 * 1024 * 1024;
    float* Ppart; half_t* Wg; half_t* Wf; half_t* Lh;
    char* ws = (char*)d_ws;
    if (fast) {
        Ppart = (float*)(ws + ((size_t)1  << 20));
        Wg    = (half_t*)(ws + ((size_t)34 << 20));
        Wf    = (half_t*)(ws + ((size_t)51 << 20));
        Lh    = (half_t*)(ws + ((size_t)68 << 20));
    } else {
        Ppart = (float*)d_out;                             // dead before k3
        Wg    = (half_t*)((char*)d_out + ((size_t)33 << 20));
        Wf    = nullptr;
        Lh    = nullptr;
    }

    k0_prep   <<<500,           256, 0, stream>>>(W, Wg, Wf, P, maxbits);
    k1_pmm    <<<dim3(500, 4),  256, 0, stream>>>(L, Wg, Ppart, Lh, maxbits);
    k1b_reduce<<<dim3(64, 5),   256, 0, stream>>>(Ppart, P);
    if (fast) {
        k23<true,  false><<<dim3(1000, 4), 256, 0, stream>>>(L, Lh, W, Wf, P, maxbits, out);
        k23<true,  true ><<<dim3(1000, 4), 256, 0, stream>>>(L, Lh, W, Wf, P, maxbits, out);
    } else {
        k23<false, false><<<dim3(1000, 4), 256, 0, stream>>>(L, Lh, W, Wf, P, maxbits, out);
        k23<false, true ><<<dim3(1000, 4), 256, 0, stream>>>(L, Lh, W, Wf, P, maxbits, out);
    }
}

// Round 3
// 369.007 us; speedup vs baseline: 1.2235x; 1.0037x over previous
//
#include <hip/hip_runtime.h>
#include <math.h>

#define ALPHA_F 0.4f
#define FP32_EPS 1.1920928955078125e-7f
#define NB 256
#define NV 128000
#define NR 64

typedef _Float16 half_t;
typedef _Float16 half2_t __attribute__((ext_vector_type(2)));
typedef _Float16 half4_t __attribute__((ext_vector_type(4)));
typedef _Float16 half8 __attribute__((ext_vector_type(8)));
typedef float f32x4 __attribute__((ext_vector_type(4)));

// ---------------------------------------------------------------------------
// Scratch layouts.
// FAST (ws_size >= 140 MB; observed ~524 MB poison fill => expect FAST):
//   ws +0      : maxbits[2]
//   ws +256    : P[256*64] f32
//   ws +1  MiB : Ppart  (500 x 4 x 64x64 f32, 32.8 MB)
//   ws +34 MiB : Wg     (k1 B-frags fp16, 16.4 MB)
//   ws +51 MiB : Wf     (k2/k3 B-frags fp16, 16.4 MB)
//   ws +68 MiB : Lh     (L as fp16, 65.5 MB)
// FALLBACK: maxbits/P in ws; Ppart @ d_out+0, Wg @ d_out+33MiB (dead before
//   k3); no Wf/Lh — k2/k3 read fp32 L and W directly.
// ---------------------------------------------------------------------------

// ---------- k0: build fp16 W fragments; zero P / maxbits ----------
// __launch_bounds__(256,4): LDS (36 KB) caps at 4 blocks/CU anyway; let the
// allocator use up to 128 VGPR so the 16 preload float4s pipeline.
__global__ __launch_bounds__(256, 4) void k0_prep(const float* __restrict__ W,
                                                  half_t* __restrict__ Wg,
                                                  half_t* __restrict__ Wf,
                                                  float* __restrict__ P,
                                                  unsigned* __restrict__ maxbits) {
    __shared__ half_t tile[256 * 72];   // stride 72 halves = 144 B (16B-aligned rows)
    const int t  = threadIdx.x;
    const int k0 = blockIdx.x * 256;

    if (blockIdx.x < 64) P[blockIdx.x * 256 + t] = 0.f;
    if (blockIdx.x == 0 && t < 2) maxbits[t] = 0u;

    // coalesced read of W[256k x 64n] tile: issue all 16 loads, then cvt->LDS
    float4 wv[16];
#pragma unroll
    for (int i = 0; i < 16; ++i) {
        const int f  = i * 256 + t;
        const int kr = f >> 4;
        const int n4 = (f & 15) * 4;
        wv[i] = *(const float4*)(W + (size_t)(k0 + kr) * NR + n4);
    }
#pragma unroll
    for (int i = 0; i < 16; ++i) {
        const int f  = i * 256 + t;
        const int kr = f >> 4;
        const int n4 = (f & 15) * 4;
        half2_t h01 = { (half_t)wv[i].x, (half_t)wv[i].y };
        half2_t h23 = { (half_t)wv[i].z, (half_t)wv[i].w };
        *(half2_t*)&tile[kr * 72 + n4]     = h01;
        *(half2_t*)&tile[kr * 72 + n4 + 2] = h23;
    }
    __syncthreads();

    // Wg: B-frags for P = L@W (transposed gather). frag(kt,nt,lane=(q,il))[j]
    //   = W[kt*32 + q*8 + j][nt*16 + il]
#pragma unroll
    for (int i = 0; i < 8; ++i) {
        const int idx  = i * 256 + t;        // 0..2047
        const int kk_l = idx >> 8;           // 0..7
        const int rem  = idx & 255;
        const int nt   = rem >> 6;
        const int lane = rem & 63;
        const int q = lane >> 4, il = lane & 15;
        half8 v;
#pragma unroll
        for (int j = 0; j < 8; ++j)
            v[j] = tile[(kk_l * 32 + q * 8 + j) * 72 + nt * 16 + il];
        const int kt = blockIdx.x * 8 + kk_l;
        *(half8*)(Wg + ((size_t)(kt * 4 + nt) * 64 + lane) * 8) = v;
    }

    // Wf: B-frags for Lp = P@W^T (no transpose). frag(vt,ks,lane=(q,il))[j]
    //   = W[vt*16 + il][ks*32 + q*8 + j]   (contiguous ds_read_b128)
    if (Wf) {
#pragma unroll
        for (int i = 0; i < 8; ++i) {
            const int idx  = i * 256 + t;
            const int vt_l = idx >> 7;       // 0..15
            const int ks   = (idx >> 6) & 1;
            const int lane = idx & 63;
            const int q = lane >> 4, il = lane & 15;
            half8 v = *(const half8*)&tile[(vt_l * 16 + il) * 72 + ks * 32 + q * 8];
            const int vt = blockIdx.x * 16 + vt_l;
            *(half8*)(Wf + ((size_t)(vt * 2 + ks) * 64 + lane) * 8) = v;
        }
    }
}

// ---------- k1: split-K MFMA partials of P = L @ W; emit Lh; max|L| ----------
// grid (500 K-chunks of 256, 4 m-quarters); block 256 = 4 waves.
// Round-2 made every global instruction contiguous (traffic == ideal, verified
// FETCH/WRITE 95.7/96.1 MB).  Round-3 fixes Little's law: VGPR was allocator-
// capped at 60 (targeting 8 waves/SIMD that LDS forbids anyway), serializing
// the stage loads at ~256 B/lane in flight -> 2.5 TB/s.  Now:
//   __launch_bounds__(256,4)  -> VGPR cap 128 (LDS caps occupancy at 4 blocks)
//   stage: issue ALL 16 float4 loads into regs (512 B/lane in flight), then
//          amax/cvt/Lh-store/LDS-store from regs
//   mfma : static 2-deep double-buffer on the Wg frag loads
__global__ __launch_bounds__(256, 4) void k1_pmm(const float* __restrict__ L,
                                                 const half_t* __restrict__ Wg,
                                                 float* __restrict__ Ppart,
                                                 half_t* __restrict__ Lh,
                                                 unsigned* __restrict__ maxbits) {
    __shared__ char lds[64 * 512];      // 64 rows x 256 halves (512 B/row), 32 KB
    __shared__ float red[4];
    const int t  = threadIdx.x;
    const int l  = t & 63;
    const int w  = t >> 6;
    const int q  = l >> 4;
    const int il = l & 15;
    const int chunk = blockIdx.x;
    const int mq    = blockIdx.y;
    const int row0  = mq * 64;
    const int col0  = chunk * 256;

    float amax = 0.f;

    // ---- phase S: stage L tile (coalesced), emit Lh, fill swizzled LDS ----
    {
        const int tr = t >> 5;          // 0..7  (row within pass-stripe)
        const int tc = t & 31;          // 0..31 (8-col chunk)
        float4 fv[16];
#pragma unroll
        for (int p = 0; p < 8; ++p) {
            const int r = p * 8 + tr;   // 0..63 ; r&7 == tr
            const float* lp = L + (size_t)(row0 + r) * NV + col0 + tc * 8;
            fv[2 * p]     = *(const float4*)lp;
            fv[2 * p + 1] = *(const float4*)(lp + 4);
        }
#pragma unroll
        for (int p = 0; p < 8; ++p) {
            const int r = p * 8 + tr;
            const float4 f0 = fv[2 * p], f1 = fv[2 * p + 1];
            amax = fmaxf(amax, fmaxf(fmaxf(fabsf(f0.x), fabsf(f0.y)),
                                     fmaxf(fabsf(f0.z), fabsf(f0.w))));
            amax = fmaxf(amax, fmaxf(fmaxf(fabsf(f1.x), fabsf(f1.y)),
                                     fmaxf(fabsf(f1.z), fabsf(f1.w))));
            half8 h = { (half_t)f0.x, (half_t)f0.y, (half_t)f0.z, (half_t)f0.w,
                        (half_t)f1.x, (half_t)f1.y, (half_t)f1.z, (half_t)f1.w };
            if (Lh) *(half8*)(Lh + (size_t)(row0 + r) * NV + col0 + tc * 8) = h;
            const int off = r * 512 + ((tc * 16) ^ (tr << 4));
            *(half8*)(lds + off) = h;
        }
    }
    __syncthreads();

    // ---- phase M: MFMA over 8 K-steps, 2-deep Wg double-buffer ----
    f32x4 acc[4] = {};
    const int arow = w * 16 + il;
    const int abase = arow * 512;
    const int axor  = (il & 7) << 4;

#define K1_LOADB(dst, kss) do {                                                  \
    const half_t* wp_ = Wg + ((size_t)((chunk * 8 + (kss)) * 4) * 64 + l) * 8;   \
    dst[0] = *(const half8*)(wp_);                                               \
    dst[1] = *(const half8*)(wp_ + 64 * 8);                                      \
    dst[2] = *(const half8*)(wp_ + 2 * 64 * 8);                                  \
    dst[3] = *(const half8*)(wp_ + 3 * 64 * 8); } while (0)

#define K1_MFMA(bv, kss) do {                                                    \
    const half8 a_ = *(const half8*)(lds + ((abase + (kss) * 64 + q * 16) ^ axor)); \
    acc[0] = __builtin_amdgcn_mfma_f32_16x16x32_f16(a_, bv[0], acc[0], 0, 0, 0); \
    acc[1] = __builtin_amdgcn_mfma_f32_16x16x32_f16(a_, bv[1], acc[1], 0, 0, 0); \
    acc[2] = __builtin_amdgcn_mfma_f32_16x16x32_f16(a_, bv[2], acc[2], 0, 0, 0); \
    acc[3] = __builtin_amdgcn_mfma_f32_16x16x32_f16(a_, bv[3], acc[3], 0, 0, 0); } while (0)

    half8 ba[4], bb[4];
    K1_LOADB(ba, 0);
#pragma unroll
    for (int ks = 0; ks < 8; ks += 2) {
        K1_LOADB(bb, ks + 1);
        K1_MFMA(ba, ks);
        if (ks + 2 < 8) K1_LOADB(ba, ks + 2);
        K1_MFMA(bb, ks + 1);
    }

    float* pb = Ppart + (size_t)(chunk * 4 + mq) * 4096;
#pragma unroll
    for (int nt = 0; nt < 4; ++nt)
#pragma unroll
        for (int i = 0; i < 4; ++i)
            pb[(w * 16 + q * 4 + i) * 64 + nt * 16 + il] = acc[nt][i];

#pragma unroll
    for (int off = 32; off > 0; off >>= 1)
        amax = fmaxf(amax, __shfl_xor(amax, off, 64));
    if (l == 0) red[w] = amax;
    __syncthreads();
    if (threadIdx.x == 0) {
        float m = fmaxf(fmaxf(red[0], red[1]), fmaxf(red[2], red[3]));
        atomicMax(&maxbits[0], __float_as_uint(m));
    }
}

// ---------- k1b: reduce Ppart -> P (atomicAdd partial sums) ----------
// grid (64, 5): y handles chunks [y*100, y*100+100)
__global__ __launch_bounds__(256) void k1b_reduce(const float* __restrict__ Ppart,
                                                  float* __restrict__ P) {
    const int g  = blockIdx.x * 256 + threadIdx.x;  // 0..16383
    const int M  = g >> 6, n = g & 63;
    const int mq = M >> 6, r = M & 63;
    const float* p = Ppart + ((size_t)(blockIdx.y * 100) * 4 + mq) * 4096 + r * 64 + n;
    float s = 0.f;
#pragma unroll 4
    for (int c = 0; c < 100; ++c) s += p[(size_t)c * 4 * 4096];
    atomicAdd(&P[g], s);
}

// ---------- k2/k3: T = P@W^T tile -> LDS; streaming epilogue ----------
// grid (1000 n-chunks of 128, 4 m-quarters); block 256; LDS T[64][132].
// __launch_bounds__(256,4): LDS (33.8 KB) caps at 4 blocks/CU anyway; phase B
// preloads all 8 global L/Lh values before the compute/store loop so the
// stream isn't latency-serialized.
template <bool FAST, bool IS_OUT>
__global__ __launch_bounds__(256, 4) void k23(const float* __restrict__ L,
                                              const half_t* __restrict__ Lh,
                                              const float* __restrict__ W,
                                              const half_t* __restrict__ Wf,
                                              const float* __restrict__ P,
                                              unsigned* __restrict__ maxbits,
                                              float* __restrict__ out) {
    __shared__ float T[64 * 132];
    __shared__ float red[4];
    const int l  = threadIdx.x & 63;
    const int w  = threadIdx.x >> 6;
    const int q  = l >> 4;
    const int il = l & 15;
    const int nc = blockIdx.x;
    const int mq = blockIdx.y;

    // phase A: MFMA 64 rows x 128 cols; wave w covers cols w*32..+32
    half8 a[4][2];
#pragma unroll
    for (int mt = 0; mt < 4; ++mt)
#pragma unroll
        for (int ks = 0; ks < 2; ++ks) {
            const float* pp = P + (size_t)(mq * 64 + mt * 16 + il) * NR + ks * 32 + q * 8;
            const float4 f0 = *(const float4*)pp;
            const float4 f1 = *(const float4*)(pp + 4);
            a[mt][ks] = { (half_t)f0.x, (half_t)f0.y, (half_t)f0.z, (half_t)f0.w,
                          (half_t)f1.x, (half_t)f1.y, (half_t)f1.z, (half_t)f1.w };
        }
#pragma unroll
    for (int ntl = 0; ntl < 2; ++ntl) {
        const int vt = nc * 8 + w * 2 + ntl;
        half8 b[2];
        if (FAST) {
#pragma unroll
            for (int ks = 0; ks < 2; ++ks)
                b[ks] = *(const half8*)(Wf + ((size_t)(vt * 2 + ks) * 64 + l) * 8);
        } else {
#pragma unroll
            for (int ks = 0; ks < 2; ++ks) {
                const float* wp = W + (size_t)(vt * 16 + il) * NR + ks * 32 + q * 8;
                const float4 f0 = *(const float4*)wp;
                const float4 f1 = *(const float4*)(wp + 4);
                b[ks] = { (half_t)f0.x, (half_t)f0.y, (half_t)f0.z, (half_t)f0.w,
                          (half_t)f1.x, (half_t)f1.y, (half_t)f1.z, (half_t)f1.w };
            }
        }
#pragma unroll
        for (int mt = 0; mt < 4; ++mt) {
            f32x4 acc = {};
            acc = __builtin_amdgcn_mfma_f32_16x16x32_f16(a[mt][0], b[0], acc, 0, 0, 0);
            acc = __builtin_amdgcn_mfma_f32_16x16x32_f16(a[mt][1], b[1], acc, 0, 0, 0);
#pragma unroll
            for (int i = 0; i < 4; ++i)
                T[(mt * 16 + q * 4 + i) * 132 + w * 32 + ntl * 16 + il] = acc[i];
        }
    }
    __syncthreads();

    // phase B: coalesced streaming over the 64x128 tile; preload all 8 global
    // reads first (64 B/lane FAST, 128 B/lane fallback in flight)
    float c1 = 0.f, mx = 0.f;
    if (IS_OUT) {
        const float maxL  = __uint_as_float(maxbits[0]);
        const float maxLp = fmaxf(__uint_as_float(maxbits[1]), FP32_EPS);
        c1 = (1.f - ALPHA_F) * (maxL / maxLp);
    }
    half4_t lhh[8];
    float4  lff[8];
#pragma unroll
    for (int i = 0; i < 8; ++i) {
        const int e = i * 1024 + threadIdx.x * 4;
        const int r = e >> 7, c = e & 127;
        const size_t gaddr = (size_t)(mq * 64 + r) * NV + nc * 128 + c;
        if (FAST) lhh[i] = *(const half4_t*)(Lh + gaddr);
        else      lff[i] = *(const float4*)(L + gaddr);
    }
#pragma unroll
    for (int i = 0; i < 8; ++i) {
        const int e = i * 1024 + threadIdx.x * 4;
        const int r = e >> 7, c = e & 127;
        const size_t gaddr = (size_t)(mq * 64 + r) * NV + nc * 128 + c;
        const float4 tv = *(const float4*)&T[r * 132 + c];
        float4 lv;
        if (FAST) lv = make_float4((float)lhh[i][0], (float)lhh[i][1],
                                   (float)lhh[i][2], (float)lhh[i][3]);
        else      lv = lff[i];
        if (IS_OUT) {
            float4 o;
            o.x = fmaf(c1, tv.x - lv.x, ALPHA_F * lv.x);
            o.y = fmaf(c1, tv.y - lv.y, ALPHA_F * lv.y);
            o.z = fmaf(c1, tv.z - lv.z, ALPHA_F * lv.z);
            o.w = fmaf(c1, tv.w - lv.w, ALPHA_F * lv.w);
            *(float4*)(out + gaddr) = o;
        } else {
            mx = fmaxf(mx, fmaxf(fmaxf(fabsf(tv.x - lv.x), fabsf(tv.y - lv.y)),
                                 fmaxf(fabsf(tv.z - lv.z), fabsf(tv.w - lv.w))));
        }
    }
    if (!IS_OUT) {
#pragma unroll
        for (int off = 32; off > 0; off >>= 1)
            mx = fmaxf(mx, __shfl_xor(mx, off, 64));
        if (l == 0) red[w] = mx;
        __syncthreads();
        if (threadIdx.x == 0) {
            float m = fmaxf(fmaxf(red[0], red[1]), fmaxf(red[2], red[3]));
            atomicMax(&maxbits[1], __float_as_uint(m));
        }
    }
}

extern "C" void kernel_launch(void* const* d_in, const int* in_sizes, int n_in,
                              void* d_out, int out_size, void* d_ws, size_t ws_size,
                              hipStream_t stream) {
    const float* L = (const float*)d_in[1];   // logits [256,128000] fp32
    const float* W = (const float*)d_in[2];   // W [128000,64] fp32
    float* out = (float*)d_out;

    unsigned* maxbits = (unsigned*)d_ws;
    float*    P       = (float*)((char*)d_ws + 256);

    const bool fast = ws_size >= (size_t)140 * 1024 * 1024;
    float* Ppart; half_t* Wg; half_t* Wf; half_t* Lh;
    char* ws = (char*)d_ws;
    if (fast) {
        Ppart = (float*)(ws + ((size_t)1  << 20));
        Wg    = (half_t*)(ws + ((size_t)34 << 20));
        Wf    = (half_t*)(ws + ((size_t)51 << 20));
        Lh    = (half_t*)(ws + ((size_t)68 << 20));
    } else {
        Ppart = (float*)d_out;                             // dead before k3
        Wg    = (half_t*)((char*)d_out + ((size_t)33 << 20));
        Wf    = nullptr;
        Lh    = nullptr;
    }

    k0_prep   <<<500,           256, 0, stream>>>(W, Wg, Wf, P, maxbits);
    k1_pmm    <<<dim3(500, 4),  256, 0, stream>>>(L, Wg, Ppart, Lh, maxbits);
    k1b_reduce<<<dim3(64, 5),   256, 0, stream>>>(Ppart, P);
    if (fast) {
        k23<true,  false><<<dim3(1000, 4), 256, 0, stream>>>(L, Lh, W, Wf, P, maxbits, out);
        k23<true,  true ><<<dim3(1000, 4), 256, 0, stream>>>(L, Lh, W, Wf, P, maxbits, out);
    } else {
        k23<false, false><<<dim3(1000, 4), 256, 0, stream>>>(L, Lh, W, Wf, P, maxbits, out);
        k23<false, true ><<<dim3(1000, 4), 256, 0, stream>>>(L, Lh, W, Wf, P, maxbits, out);
    }
}